// Round 2
// baseline (8233.775 us; speedup 1.0000x reference)
//
#include <hip/hip_runtime.h>

typedef unsigned short u16;
typedef unsigned int   u32;

#define ATT_EPS 1e-6f
#define LN_EPS  1e-5f

__device__ __forceinline__ float bflo(u32 u){ return __uint_as_float(u << 16); }
__device__ __forceinline__ float bfhi(u32 u){ return __uint_as_float(u & 0xffff0000u); }
__device__ __forceinline__ u16 f2b(float f){
  u32 x = __float_as_uint(f);
  return (u16)((x + 0x7fffu + ((x >> 16) & 1u)) >> 16);   // RNE
}
__device__ __forceinline__ float elup1(float x){ return x > 0.f ? x + 1.f : __expf(x); }

#define UNPACK8(dst, off, u) do { \
  dst[(off)+0]=bflo((u).x); dst[(off)+1]=bfhi((u).x); \
  dst[(off)+2]=bflo((u).y); dst[(off)+3]=bfhi((u).y); \
  dst[(off)+4]=bflo((u).z); dst[(off)+5]=bfhi((u).z); \
  dst[(off)+6]=bflo((u).w); dst[(off)+7]=bfhi((u).w); } while(0)

#define FMA_TILE(ACC, A, W0_, W1_, W2_, W3_) do { \
  const float _w0=(W0_), _w1=(W1_), _w2=(W2_), _w3=(W3_); \
  _Pragma("unroll") \
  for (int _i = 0; _i < 16; ++_i) { \
    ACC[_i][0] = fmaf(A[_i], _w0, ACC[_i][0]); \
    ACC[_i][1] = fmaf(A[_i], _w1, ACC[_i][1]); \
    ACC[_i][2] = fmaf(A[_i], _w2, ACC[_i][2]); \
    ACC[_i][3] = fmaf(A[_i], _w3, ACC[_i][3]); \
  } } while(0)

// One block per 8x8 window (L=64 tokens, C=256).  256 threads.
// Thread tile: rows r0..r0+15 (r0 = 16*(t>>6), per-wave), cols c0..c0+3 (c0 = 4*(t&63)).
// ALL global tensors are fp32 (reference dtype). LDS intermediates bf16-packed.
__global__ __launch_bounds__(256, 1)
void lgattn(const float* __restrict__ xg,  const float* __restrict__ Wq,
            const float* __restrict__ Wk,  const float* __restrict__ Wv,
            const float* __restrict__ Wm,  const float* __restrict__ W1,
            const float* __restrict__ W2,  const float* __restrict__ g1,
            const float* __restrict__ b1,  const float* __restrict__ g2,
            const float* __restrict__ b2,  float* __restrict__ outg)
{
  __shared__ float xT[256*64];      // 64 KB : x fp32, transposed [c][l]
  __shared__ float kvbuf[8192];     // 32 KB : K(bf16 [s][c]) -> KV(f32 [c=(h,d)][vc]) -> msg_attT(bf16 [c][l]) -> htileT(bf16 [c][l])
  __shared__ u16   bufB[256*64];    // 32 KB : V(bf16 [s][c]) -> Q(bf16 [s][c]) -> msgT(bf16 [c][l], post-LN1)
  __shared__ float ksumS[256];      // 1 KB  : sum_s K[s][c]

  const int t    = threadIdx.x;
  const int lane = t & 63;
  const int rg   = t >> 6;          // wave id == row group
  const int r0   = rg * 16;
  const int c0   = lane * 4;

  const int win = blockIdx.x;
  const int b   = win / 900;
  const int rem = win - b * 900;
  const int wh  = rem / 30;
  const int ww  = rem - wh * 30;
  const long long rowbase = ((long long)b * 240 + wh * 8) * 240 + ww * 8;
  // token l -> global row = rowbase + (l>>3)*240 + (l&7)

  // ---------- stage x -> xT (fp32, [c][l]) ----------
  #pragma unroll 4
  for (int i = 0; i < 16; ++i) {
    const int l = r0 + i;
    const long long row = rowbase + (l >> 3) * 240 + (l & 7);
    const float4 u = *(const float4*)(xg + row * 256 + c0);
    xT[(c0+0)*64 + l] = u.x;
    xT[(c0+1)*64 + l] = u.y;
    xT[(c0+2)*64 + l] = u.z;
    xT[(c0+3)*64 + l] = u.w;
  }
  __syncthreads();

  // GEMM with A = xT (fp32, broadcast reads), K=256, W row-major fp32, leading dim ldw
  auto gemm_xT = [&](const float* __restrict__ W, int ldw, float acc[16][4]) {
    #pragma unroll 2
    for (int kk = 0; kk < 256; ++kk) {
      const float4 a0 = *(const float4*)&xT[kk*64 + r0 + 0];
      const float4 a1 = *(const float4*)&xT[kk*64 + r0 + 4];
      const float4 a2 = *(const float4*)&xT[kk*64 + r0 + 8];
      const float4 a3 = *(const float4*)&xT[kk*64 + r0 + 12];
      const float4 w = *(const float4*)(W + kk*ldw + c0);
      const float a[16] = {a0.x,a0.y,a0.z,a0.w, a1.x,a1.y,a1.z,a1.w,
                           a2.x,a2.y,a2.z,a2.w, a3.x,a3.y,a3.z,a3.w};
      FMA_TILE(acc, a, w.x, w.y, w.z, w.w);
    }
  };

  // GEMM with A = bf16 LDS in transposed layout [kk][l], K=256, W fp32
  auto gemm_bf = [&](const u16* __restrict__ A, const float* __restrict__ W, int ldw, float acc[16][4]) {
    #pragma unroll 2
    for (int kk = 0; kk < 256; ++kk) {
      const uint4 a01 = *(const uint4*)&A[kk*64 + r0];
      const uint4 a23 = *(const uint4*)&A[kk*64 + r0 + 8];
      float a[16];
      UNPACK8(a, 0, a01); UNPACK8(a, 8, a23);
      const float4 w = *(const float4*)(W + kk*ldw + c0);
      FMA_TILE(acc, a, w.x, w.y, w.z, w.w);
    }
  };

  // ---------- V = x @ Wv -> bufB bf16 [s][c] ----------
  {
    float acc[16][4] = {{0.f}};
    gemm_xT(Wv, 256, acc);
    #pragma unroll
    for (int i = 0; i < 16; ++i)
      #pragma unroll
      for (int j = 0; j < 4; ++j)
        bufB[(r0+i)*256 + c0 + j] = f2b(acc[i][j]);
  }
  __syncthreads();

  // ---------- K = elu(x @ Wk)+1 -> kvbuf bf16 [s][c] ----------
  {
    float acc[16][4] = {{0.f}};
    gemm_xT(Wk, 256, acc);
    u16* kb = (u16*)kvbuf;
    #pragma unroll
    for (int i = 0; i < 16; ++i)
      #pragma unroll
      for (int j = 0; j < 4; ++j)
        kb[(r0+i)*256 + c0 + j] = f2b(elup1(acc[i][j]));
  }
  __syncthreads();

  // ---------- KV[h,d,:] and Ksum: thread t = (h = t>>5, d = t&31) ----------
  {
    const int h = t >> 5;
    const u16* kb = (const u16*)kvbuf;
    float kv[32] = {0.f};
    float ks = 0.f;
    #pragma unroll 2
    for (int s = 0; s < 64; ++s) {
      const float kc = bflo((u32)kb[s*256 + t]);        // K[s][t]
      ks += kc;
      const uint4 v0 = *(const uint4*)&bufB[s*256 + h*32 + 0];
      const uint4 v1 = *(const uint4*)&bufB[s*256 + h*32 + 8];
      const uint4 v2 = *(const uint4*)&bufB[s*256 + h*32 + 16];
      const uint4 v3 = *(const uint4*)&bufB[s*256 + h*32 + 24];
      float vv[32];
      UNPACK8(vv, 0, v0); UNPACK8(vv, 8, v1); UNPACK8(vv, 16, v2); UNPACK8(vv, 24, v3);
      #pragma unroll
      for (int d = 0; d < 32; ++d) kv[d] = fmaf(kc, vv[d], kv[d]);
    }
    __syncthreads();                 // all K reads done before overwriting kvbuf
    ksumS[t] = ks;
    #pragma unroll
    for (int q = 0; q < 8; ++q)
      *(float4*)&kvbuf[t*32 + 4*q] = make_float4(kv[4*q], kv[4*q+1], kv[4*q+2], kv[4*q+3]);
  }
  __syncthreads();

  // ---------- Q = elu(x @ Wq)+1 -> bufB bf16 [s][c] (V dead) ----------
  {
    float acc[16][4] = {{0.f}};
    gemm_xT(Wq, 256, acc);
    #pragma unroll
    for (int i = 0; i < 16; ++i)
      #pragma unroll
      for (int j = 0; j < 4; ++j)
        bufB[(r0+i)*256 + c0 + j] = f2b(elup1(acc[i][j]));
  }
  __syncthreads();

  // ---------- attention: msg_att[l, c=(h,vc)] = (Q_l . KV[h,:,vc]) / (eps + Q_l . Ksum[h]) ----------
  // (the reference's v/L and *L cancel exactly: L = 64 is a power of two)
  {
    const int h = t >> 5, vc = t & 31;
    float kvcol[32], kss[32];
    #pragma unroll
    for (int d = 0; d < 32; ++d) kvcol[d] = kvbuf[(h*32 + d)*32 + vc];
    #pragma unroll
    for (int d = 0; d < 32; ++d) kss[d]  = ksumS[h*32 + d];
    __syncthreads();                 // KV fully consumed into regs; kvbuf now writable
    u32* mout = (u32*)kvbuf;         // msg_attT bf16 [c][l]
    #pragma unroll 2
    for (int l2 = 0; l2 < 32; ++l2) {
      float r[2];
      #pragma unroll
      for (int ii = 0; ii < 2; ++ii) {
        const int l = 2*l2 + ii;
        const uint4 q0 = *(const uint4*)&bufB[l*256 + h*32 + 0];
        const uint4 q1 = *(const uint4*)&bufB[l*256 + h*32 + 8];
        const uint4 q2 = *(const uint4*)&bufB[l*256 + h*32 + 16];
        const uint4 q3 = *(const uint4*)&bufB[l*256 + h*32 + 24];
        float qv[32];
        UNPACK8(qv, 0, q0); UNPACK8(qv, 8, q1); UNPACK8(qv, 16, q2); UNPACK8(qv, 24, q3);
        float num = 0.f, den = ATT_EPS;
        #pragma unroll
        for (int d = 0; d < 32; ++d) {
          num = fmaf(qv[d], kvcol[d], num);
          den = fmaf(qv[d], kss[d],  den);
        }
        r[ii] = num / den;
      }
      mout[t*32 + l2] = (u32)f2b(r[0]) | ((u32)f2b(r[1]) << 16);
    }
  }
  __syncthreads();

  // ---------- msg = LN1(msg_att @ Wm) -> bufB bf16 [c][l] (Q dead) ----------
  {
    float acc[16][4] = {{0.f}};
    gemm_bf((const u16*)kvbuf, Wm, 256, acc);
    const float4 gu = *(const float4*)(g1 + c0);
    const float4 bu = *(const float4*)(b1 + c0);
    const float gv[4] = {gu.x, gu.y, gu.z, gu.w};
    const float bv[4] = {bu.x, bu.y, bu.z, bu.w};
    #pragma unroll
    for (int i = 0; i < 16; ++i) {
      float s  = acc[i][0] + acc[i][1] + acc[i][2] + acc[i][3];
      float sq = acc[i][0]*acc[i][0] + acc[i][1]*acc[i][1]
               + acc[i][2]*acc[i][2] + acc[i][3]*acc[i][3];
      #pragma unroll
      for (int m = 1; m < 64; m <<= 1) { s += __shfl_xor(s, m, 64); sq += __shfl_xor(sq, m, 64); }
      const float mean = s * (1.f/256.f);
      const float rstd = rsqrtf(sq * (1.f/256.f) - mean*mean + LN_EPS);
      #pragma unroll
      for (int j = 0; j < 4; ++j)
        bufB[(c0+j)*64 + r0 + i] = f2b((acc[i][j] - mean) * rstd * gv[j] + bv[j]);
    }
  }
  __syncthreads();

  // ---------- MLP: h = relu([x, msg] @ W1); out2 = h @ W2; LN2; + x ----------
  {
    float oacc[16][4] = {{0.f}};
    for (int jt = 0; jt < 2; ++jt) {
      float hacc[16][4] = {{0.f}};
      gemm_xT(W1 + jt*256, 512, hacc);                       // k = 0..255 : x part
      gemm_bf(bufB, W1 + 256*512 + jt*256, 512, hacc);       // k = 256..511 : msg part
      __syncthreads();               // prior kvbuf readers (Wm gemm / previous MLP2) done
      u16* ht = (u16*)kvbuf;         // htileT bf16 [c][l]
      #pragma unroll
      for (int i = 0; i < 16; ++i)
        #pragma unroll
        for (int j = 0; j < 4; ++j)
          ht[(c0+j)*64 + r0 + i] = f2b(fmaxf(hacc[i][j], 0.f));
      __syncthreads();
      gemm_bf((const u16*)kvbuf, W2 + jt*256*256, 256, oacc);
    }

    const float4 gu = *(const float4*)(g2 + c0);
    const float4 bu = *(const float4*)(b2 + c0);
    const float gv[4] = {gu.x, gu.y, gu.z, gu.w};
    const float bv[4] = {bu.x, bu.y, bu.z, bu.w};
    #pragma unroll
    for (int i = 0; i < 16; ++i) {
      float s  = oacc[i][0] + oacc[i][1] + oacc[i][2] + oacc[i][3];
      float sq = oacc[i][0]*oacc[i][0] + oacc[i][1]*oacc[i][1]
               + oacc[i][2]*oacc[i][2] + oacc[i][3]*oacc[i][3];
      #pragma unroll
      for (int m = 1; m < 64; m <<= 1) { s += __shfl_xor(s, m, 64); sq += __shfl_xor(sq, m, 64); }
      const float mean = s * (1.f/256.f);
      const float rstd = rsqrtf(sq * (1.f/256.f) - mean*mean + LN_EPS);
      const int l = r0 + i;
      const long long row = rowbase + (l >> 3) * 240 + (l & 7);
      const float4 xu = *(const float4*)(xg + row*256 + c0);
      float4 st;
      st.x = (oacc[i][0] - mean) * rstd * gv[0] + bv[0] + xu.x;
      st.y = (oacc[i][1] - mean) * rstd * gv[1] + bv[1] + xu.y;
      st.z = (oacc[i][2] - mean) * rstd * gv[2] + bv[2] + xu.z;
      st.w = (oacc[i][3] - mean) * rstd * gv[3] + bv[3] + xu.w;
      *(float4*)(outg + row*256 + c0) = st;
    }
  }
}

extern "C" void kernel_launch(void* const* d_in, const int* in_sizes, int n_in,
                              void* d_out, int out_size, void* d_ws, size_t ws_size,
                              hipStream_t stream) {
  const float* xg  = (const float*)d_in[0];
  const float* Wq  = (const float*)d_in[1];
  const float* Wk  = (const float*)d_in[2];
  const float* Wv  = (const float*)d_in[3];
  const float* Wm  = (const float*)d_in[4];
  const float* W1  = (const float*)d_in[5];
  const float* W2  = (const float*)d_in[6];
  const float* g1  = (const float*)d_in[7];
  const float* b1  = (const float*)d_in[8];
  const float* g2  = (const float*)d_in[9];
  const float* b2  = (const float*)d_in[10];
  float* outg = (float*)d_out;

  const int B = in_sizes[0] / (240 * 240 * 256);
  const int nwin = B * 30 * 30;   // one block per 8x8 window

  lgattn<<<dim3(nwin), dim3(256), 0, stream>>>(xg, Wq, Wk, Wv, Wm, W1, W2,
                                               g1, b1, g2, b2, outg);
}